// Round 1
// baseline (997.868 us; speedup 1.0000x reference)
//
#include <hip/hip_runtime.h>
#include <cstdint>
#include <cstddef>

// Problem constants
#define T_TOK 8192
#define K_CODE 8192
#define C_DIM 512
#define BETA 0.25f
#define DECAY 0.99f
#define ONE_MINUS_DECAY 0.01f   // float32(0.01) == float32(1.0-0.99 in f64) = 0.009999999776
#define EPS_F 1e-5f
#define K_EPS 0.08192f          // K * EPS in f64, rounded to f32

// d_out layout (floats, concatenated in reference return order)
#define ZQ_OFF   ((size_t)0)          // z_q_st      [8,1024,512] = 4194304
#define IDX_OFF  ((size_t)4194304)    // indices     [8,1024]     = 8192
#define LOSS_OFF ((size_t)4202496)    // vq_loss     scalar       = 1
#define NCB_OFF  ((size_t)4202497)    // new_codebook[8192,512]   = 4194304
#define NCS_OFF  ((size_t)8396801)    // new_cluster [8192]       = 8192
#define NEA_OFF  ((size_t)8404993)    // new_embed_avg[8192,512]  = 4194304

// d_ws layout (float offsets)
#define WS_ZNORM 0
#define WS_ENORM 8192
#define WS_COUNT 16384
#define WS_NSUM  24576
#define WS_BEST  24578   // u64[8192]; byte offset 98312, 8-aligned

__device__ inline unsigned long long shfl_xor_u64(unsigned long long v, int m) {
    int lo = (int)(unsigned)(v & 0xFFFFFFFFull);
    int hi = (int)(unsigned)(v >> 32);
    lo = __shfl_xor(lo, m, 64);
    hi = __shfl_xor(hi, m, 64);
    return ((unsigned long long)(unsigned)hi << 32) | (unsigned)(unsigned)lo;
}

// ---- K1: row norms of z (tokens) and codebook (codes) -----------------------
__global__ __launch_bounds__(256) void norms_kernel(const float* __restrict__ z,
                                                    const float* __restrict__ cb,
                                                    float* __restrict__ ws) {
    int row = blockIdx.x;           // 0..16383
    int tid = threadIdx.x;
    const float* p;
    float* dst;
    if (row < T_TOK) { p = z + (size_t)row * C_DIM;          dst = ws + WS_ZNORM + row; }
    else             { p = cb + (size_t)(row - T_TOK) * C_DIM; dst = ws + WS_ENORM + (row - T_TOK); }
    float a = p[tid], b = p[tid + 256];
    float s = a * a + b * b;
    #pragma unroll
    for (int m = 32; m; m >>= 1) s += __shfl_down(s, m, 64);
    __shared__ float red[4];
    if ((tid & 63) == 0) red[tid >> 6] = s;
    __syncthreads();
    if (tid == 0) dst[0] = (red[0] + red[1]) + (red[2] + red[3]);
}

// ---- K2: distance GEMM + fused argmin ---------------------------------------
// Tile: 128(M tokens) x 128(N codes), BK=16. 256 threads = 16x16, each thread
// computes a 2x2 grid of 4x4 microtiles (rows {ty*4+i, 64+ty*4+i}, cols
// {tx*4+j, 64+tx*4+j}). LDS stored transposed [kk][m] with stride 132:
// staging writes are exactly 2-way bank aliased (free), frag reads are
// conflict-free ds_read_b128.
__global__ __launch_bounds__(256, 4) void dist_argmin_kernel(
        const float* __restrict__ z, const float* __restrict__ cb,
        const float* __restrict__ znorm, const float* __restrict__ enorm,
        unsigned long long* __restrict__ best) {
    __shared__ float As[16][132];
    __shared__ float Bs[16][132];
    const int tid = threadIdx.x;
    const int tx = tid & 15, ty = tid >> 4;
    const int mBase = blockIdx.x * 128;
    const int nBase = blockIdx.y * 128;

    float acc[2][2][4][4];
    #pragma unroll
    for (int i2 = 0; i2 < 2; ++i2)
        #pragma unroll
        for (int j2 = 0; j2 < 2; ++j2)
            #pragma unroll
            for (int i = 0; i < 4; ++i)
                #pragma unroll
                for (int j = 0; j < 4; ++j) acc[i2][j2][i][j] = 0.0f;

    for (int k0 = 0; k0 < C_DIM; k0 += 16) {
        __syncthreads();
        #pragma unroll
        for (int s = 0; s < 2; ++s) {
            int f = tid + s * 256;
            int row = f >> 2;            // 0..127
            int c4 = (f & 3) << 2;       // 0,4,8,12
            float4 av = *(const float4*)(z  + (size_t)(mBase + row) * C_DIM + k0 + c4);
            float4 bv = *(const float4*)(cb + (size_t)(nBase + row) * C_DIM + k0 + c4);
            As[c4 + 0][row] = av.x; As[c4 + 1][row] = av.y;
            As[c4 + 2][row] = av.z; As[c4 + 3][row] = av.w;
            Bs[c4 + 0][row] = bv.x; Bs[c4 + 1][row] = bv.y;
            Bs[c4 + 2][row] = bv.z; Bs[c4 + 3][row] = bv.w;
        }
        __syncthreads();
        #pragma unroll
        for (int kk = 0; kk < 16; ++kk) {
            float a[2][4], b[2][4];
            *(float4*)a[0] = *(const float4*)&As[kk][ty * 4];
            *(float4*)a[1] = *(const float4*)&As[kk][64 + ty * 4];
            *(float4*)b[0] = *(const float4*)&Bs[kk][tx * 4];
            *(float4*)b[1] = *(const float4*)&Bs[kk][64 + tx * 4];
            #pragma unroll
            for (int i2 = 0; i2 < 2; ++i2)
                #pragma unroll
                for (int i = 0; i < 4; ++i)
                    #pragma unroll
                    for (int j2 = 0; j2 < 2; ++j2)
                        #pragma unroll
                        for (int j = 0; j < 4; ++j)
                            acc[i2][j2][i][j] = fmaf(a[i2][i], b[j2][j], acc[i2][j2][i][j]);
        }
    }

    // Epilogue: dist = (znorm - 2*dot) + enorm  (mimics reference association
    // order so our 512-magnitude rounding tracks the reference's), then
    // per-row argmin across the 128-code tile, then global u64 atomicMin.
    #pragma unroll
    for (int i2 = 0; i2 < 2; ++i2) {
        #pragma unroll
        for (int i = 0; i < 4; ++i) {
            int m = mBase + i2 * 64 + ty * 4 + i;
            float zn = znorm[m];
            unsigned long long bestp = ~0ULL;
            #pragma unroll
            for (int j2 = 0; j2 < 2; ++j2) {
                #pragma unroll
                for (int j = 0; j < 4; ++j) {
                    int n = nBase + j2 * 64 + tx * 4 + j;
                    float s = (zn - 2.0f * acc[i2][j2][i][j]) + enorm[n];
                    unsigned long long p =
                        ((unsigned long long)__float_as_uint(s) << 32) | (unsigned)n;
                    bestp = p < bestp ? p : bestp;
                }
            }
            #pragma unroll
            for (int msk = 1; msk < 16; msk <<= 1) {
                unsigned long long o = shfl_xor_u64(bestp, msk);
                bestp = o < bestp ? o : bestp;
            }
            if (tx == 0) atomicMin(&best[m], bestp);
        }
    }
}

// ---- K3: gather z_q, z_q_st, loss partial, counts, embed_sum scatter --------
__global__ __launch_bounds__(256) void gather_kernel(
        const float* __restrict__ z, const float* __restrict__ cb,
        const unsigned long long* __restrict__ best,
        float* __restrict__ out, float* __restrict__ counts) {
    int t = blockIdx.x;
    int tid = threadIdx.x;
    int idx = (int)(unsigned)(best[t] & 0xFFFFFFFFull);
    const float* zr = z + (size_t)t * C_DIM;
    const float* qr = cb + (size_t)idx * C_DIM;
    float lsum = 0.0f;
    #pragma unroll
    for (int s = 0; s < 2; ++s) {
        int c = tid + s * 256;
        float zf = zr[c], qf = qr[c];
        // straight-through: z + (z_q - z), computed literally in fp32
        out[ZQ_OFF + (size_t)t * C_DIM + c] = zf + (qf - zf);
        float d = zf - qf;
        lsum += d * d;
        atomicAdd(&out[NEA_OFF + (size_t)idx * C_DIM + c], zf);  // raw embed_sum
    }
    #pragma unroll
    for (int m = 32; m; m >>= 1) lsum += __shfl_down(lsum, m, 64);
    __shared__ float red[4];
    if ((tid & 63) == 0) red[tid >> 6] = lsum;
    __syncthreads();
    if (tid == 0) {
        float tot = (red[0] + red[1]) + (red[2] + red[3]);
        atomicAdd(&out[LOSS_OFF], tot * (BETA / ((float)T_TOK * (float)C_DIM)));
        out[IDX_OFF + t] = (float)idx;
        atomicAdd(&counts[idx], 1.0f);
    }
}

// ---- K4: new_cluster_size + n = sum(ncs) ------------------------------------
__global__ __launch_bounds__(256) void ncs_kernel(const float* __restrict__ cs,
                                                  const float* __restrict__ counts,
                                                  float* __restrict__ out,
                                                  float* __restrict__ nsum) {
    int k = blockIdx.x * 256 + threadIdx.x;
    float v = cs[k] * DECAY + counts[k] * ONE_MINUS_DECAY;
    out[NCS_OFF + k] = v;
    float s = v;
    #pragma unroll
    for (int m = 32; m; m >>= 1) s += __shfl_down(s, m, 64);
    __shared__ float red[4];
    int tid = threadIdx.x;
    if ((tid & 63) == 0) red[tid >> 6] = s;
    __syncthreads();
    if (tid == 0) atomicAdd(nsum, (red[0] + red[1]) + (red[2] + red[3]));
}

// ---- K5: finalize new_embed_avg (in place) and new_codebook -----------------
__global__ __launch_bounds__(256) void finalize_kernel(const float* __restrict__ ea,
                                                       float* __restrict__ out,
                                                       const float* __restrict__ nsumP) {
    int k = blockIdx.x;
    int tid = threadIdx.x;
    float n = fmaxf(*nsumP, 1.0f);
    float ncs = out[NCS_OFF + k];
    float smoothed = ((ncs + EPS_F) / (n + K_EPS)) * n;
    #pragma unroll
    for (int s = 0; s < 2; ++s) {
        int c = tid + s * 256;
        size_t o = (size_t)k * C_DIM + c;
        float es = out[NEA_OFF + o];                       // scattered embed_sum
        float nea = ea[o] * DECAY + es * ONE_MINUS_DECAY;
        out[NEA_OFF + o] = nea;
        out[NCB_OFF + o] = nea / smoothed;
    }
}

extern "C" void kernel_launch(void* const* d_in, const int* in_sizes, int n_in,
                              void* d_out, int out_size, void* d_ws, size_t ws_size,
                              hipStream_t stream) {
    const float* z  = (const float*)d_in[0];   // z_e        [8,1024,512]
    const float* cb = (const float*)d_in[1];   // codebook   [8192,512]
    const float* cs = (const float*)d_in[2];   // cluster_size [8192]
    const float* ea = (const float*)d_in[3];   // embed_avg  [8192,512]
    float* out = (float*)d_out;
    float* ws  = (float*)d_ws;
    unsigned long long* best = (unsigned long long*)(ws + WS_BEST);

    // Init accumulators (harness re-poisons d_out/d_ws to 0xAA before every launch)
    hipMemsetAsync(ws + WS_COUNT, 0, (size_t)(8192 + 2) * 4, stream);       // counts + nsum
    hipMemsetAsync(ws + WS_BEST, 0xFF, (size_t)8192 * 8, stream);           // best = u64 max
    hipMemsetAsync(out + LOSS_OFF, 0, 4, stream);                           // loss accumulator
    hipMemsetAsync(out + NEA_OFF, 0, (size_t)4194304 * 4, stream);          // embed_sum accum

    norms_kernel<<<16384, 256, 0, stream>>>(z, cb, ws);
    dist_argmin_kernel<<<dim3(64, 64), 256, 0, stream>>>(z, cb, ws + WS_ZNORM, ws + WS_ENORM, best);
    gather_kernel<<<8192, 256, 0, stream>>>(z, cb, best, out, ws + WS_COUNT);
    ncs_kernel<<<32, 256, 0, stream>>>(cs, ws + WS_COUNT, out, ws + WS_NSUM);
    finalize_kernel<<<8192, 256, 0, stream>>>(ea, out, ws + WS_NSUM);
}

// Round 2
// 563.124 us; speedup vs baseline: 1.7720x; 1.7720x over previous
//
#include <hip/hip_runtime.h>
#include <cstdint>
#include <cstddef>

// Problem constants
#define T_TOK 8192
#define K_CODE 8192
#define C_DIM 512
#define BETA 0.25f
#define DECAY 0.99f
#define ONE_MINUS_DECAY 0.01f
#define EPS_F 1e-5f
#define K_EPS 0.08192f

// d_out layout (floats, concatenated in reference return order)
#define ZQ_OFF   ((size_t)0)          // z_q_st      [8,1024,512] = 4194304
#define IDX_OFF  ((size_t)4194304)    // indices     [8,1024]     = 8192
#define LOSS_OFF ((size_t)4202496)    // vq_loss     scalar       = 1
#define NCB_OFF  ((size_t)4202497)    // new_codebook[8192,512]   = 4194304
#define NCS_OFF  ((size_t)8396801)    // new_cluster [8192]       = 8192
#define NEA_OFF  ((size_t)8404993)    // new_embed_avg[8192,512]  = 4194304

// Packed fp16-split operands live INSIDE d_out (consumed by the GEMM before
// the tail kernels overwrite these regions; all stream-ordered):
//   zp: halfs [0, 12582912)         = floats [0, 6291456)
//   cp: halfs [12582912, 25165824)  = floats [6291456, 12582912)
#define CP_HALF_OFF ((size_t)12582912)

// d_ws layout (float offsets) — small scratch only
#define WS_ZNORM 0
#define WS_ENORM 8192
#define WS_COUNT 16384
#define WS_NSUM  24576
#define WS_BEST  24578   // u64[8192]; byte offset 98312, 8-aligned

typedef _Float16 half8 __attribute__((ext_vector_type(8)));
typedef float floatx4 __attribute__((ext_vector_type(4)));

__device__ __forceinline__ void gload16(const void* g, void* l) {
    __builtin_amdgcn_global_load_lds(
        (const __attribute__((address_space(1))) void*)g,
        (__attribute__((address_space(3))) void*)l, 16, 0, 0);
}

__device__ inline unsigned long long shfl_xor_u64(unsigned long long v, int m) {
    int lo = (int)(unsigned)(v & 0xFFFFFFFFull);
    int hi = (int)(unsigned)(v >> 32);
    lo = __shfl_xor(lo, m, 64);
    hi = __shfl_xor(hi, m, 64);
    return ((unsigned long long)(unsigned)hi << 32) | (unsigned)(unsigned)lo;
}

// ---- K1: fp16 hi/lo split pack + row norms ----------------------------------
// z rows -> zp = [hx | hx | lx]; cb rows -> cp = [hy | ly | hy]
// so sum_k zp[m,k]*cp[n,k] = hx.hy + hx.ly + lx.hy ~= x.y to ~2^-23 rel.
// Norms computed with EXACTLY round-1's reduction order (it passed).
__global__ __launch_bounds__(256) void prep_kernel(const float* __restrict__ z,
                                                   const float* __restrict__ cb,
                                                   _Float16* __restrict__ zp,
                                                   _Float16* __restrict__ cp,
                                                   float* __restrict__ ws) {
    int row = blockIdx.x;           // 0..16383
    int tid = threadIdx.x;
    const float* src;
    _Float16* dst;
    float* nrm;
    bool isZ = row < T_TOK;
    if (isZ) { src = z + (size_t)row * C_DIM; dst = zp + (size_t)row * 1536; nrm = ws + WS_ZNORM + row; }
    else { int r = row - T_TOK; src = cb + (size_t)r * C_DIM; dst = cp + (size_t)r * 1536; nrm = ws + WS_ENORM + r; }

    float a = src[tid], b = src[tid + 256];
    _Float16 ha = (_Float16)a, hb = (_Float16)b;
    _Float16 la = (_Float16)(a - (float)ha);
    _Float16 lb = (_Float16)(b - (float)hb);
    if (isZ) {
        dst[tid] = ha;        dst[tid + 256] = hb;
        dst[512 + tid] = ha;  dst[768 + tid] = hb;
        dst[1024 + tid] = la; dst[1280 + tid] = lb;
    } else {
        dst[tid] = ha;        dst[tid + 256] = hb;
        dst[512 + tid] = la;  dst[768 + tid] = lb;
        dst[1024 + tid] = ha; dst[1280 + tid] = hb;
    }

    float s = a * a + b * b;
    #pragma unroll
    for (int m = 32; m; m >>= 1) s += __shfl_down(s, m, 64);
    __shared__ float red[4];
    if ((tid & 63) == 0) red[tid >> 6] = s;
    __syncthreads();
    if (tid == 0) nrm[0] = (red[0] + red[1]) + (red[2] + red[3]);
}

// ---- K2: MFMA distance GEMM + fused argmin ----------------------------------
// 128x128 tile, BK=32, 4 waves in 2x2, each wave 64x64 via 4x4 grid of
// 16x16x32 f16 MFMAs. Staging via global_load_lds width=16 (wave-uniform
// base + lane*16 -> packed [row][k] LDS layout, conflict-free b128 frag reads).
__global__ __launch_bounds__(256) void dist_mfma_kernel(
        const _Float16* __restrict__ zp, const _Float16* __restrict__ cp,
        const float* __restrict__ znorm, const float* __restrict__ enorm,
        unsigned long long* __restrict__ best) {
    __shared__ __align__(16) _Float16 As[128 * 32];
    __shared__ __align__(16) _Float16 Bs[128 * 32];
    const int tid = threadIdx.x;
    const int w = tid >> 6, lane = tid & 63;
    const int quad = lane >> 4, lr = lane & 15;
    const int wm = w >> 1, wn = w & 1;

    // grouped swizzle for L2 locality: 16x64 supergroups
    const int GRID_N = 64, GROUP_M = 16;
    int pid = blockIdx.x;
    int per = GROUP_M * GRID_N;
    int g = pid / per;
    int local = pid % per;
    int bm = g * GROUP_M + (local & (GROUP_M - 1));
    int bn = local / GROUP_M;
    const int mBase = bm * 128, nBase = bn * 128;

    // staging: 8 x 1KB instructions cover each 8KB tile; wave w issues 2 for A, 2 for B
    int r0 = (w * 2 + 0) * 16 + (lane >> 2);
    int r1 = (w * 2 + 1) * 16 + (lane >> 2);
    int cq = (lane & 3) * 8;
    const _Float16* ga0 = zp + (size_t)(mBase + r0) * 1536 + cq;
    const _Float16* ga1 = zp + (size_t)(mBase + r1) * 1536 + cq;
    const _Float16* gb0 = cp + (size_t)(nBase + r0) * 1536 + cq;
    const _Float16* gb1 = cp + (size_t)(nBase + r1) * 1536 + cq;
    _Float16* la0 = As + (w * 2 + 0) * 512;
    _Float16* la1 = As + (w * 2 + 1) * 512;
    _Float16* lb0 = Bs + (w * 2 + 0) * 512;
    _Float16* lb1 = Bs + (w * 2 + 1) * 512;

    const _Float16* aFrag = As + ((size_t)(wm * 64 + lr)) * 32 + quad * 8;
    const _Float16* bFrag = Bs + ((size_t)(wn * 64 + lr)) * 32 + quad * 8;

    floatx4 acc[4][4] = {};

    for (int it = 0; it < 48; ++it) {
        __syncthreads();
        gload16(ga0, la0);
        gload16(ga1, la1);
        gload16(gb0, lb0);
        gload16(gb1, lb1);
        ga0 += 32; ga1 += 32; gb0 += 32; gb1 += 32;
        __syncthreads();
        half8 af[4], bf[4];
        #pragma unroll
        for (int i = 0; i < 4; ++i) af[i] = *(const half8*)(aFrag + i * 16 * 32);
        #pragma unroll
        for (int j = 0; j < 4; ++j) bf[j] = *(const half8*)(bFrag + j * 16 * 32);
        #pragma unroll
        for (int i = 0; i < 4; ++i)
            #pragma unroll
            for (int j = 0; j < 4; ++j)
                acc[i][j] = __builtin_amdgcn_mfma_f32_16x16x32_f16(af[i], bf[j], acc[i][j], 0, 0, 0);
    }

    // Epilogue: dist = (znorm - 2*dot) + enorm, same association as round 1.
    // C/D layout (16x16x32): col = lane&15, row = quad*4 + reg.
    float en[4];
    #pragma unroll
    for (int j = 0; j < 4; ++j) en[j] = enorm[nBase + wn * 64 + j * 16 + lr];
    #pragma unroll
    for (int i = 0; i < 4; ++i) {
        #pragma unroll
        for (int r = 0; r < 4; ++r) {
            int m = mBase + wm * 64 + i * 16 + quad * 4 + r;
            float zn = znorm[m];
            unsigned long long bestp = ~0ULL;
            #pragma unroll
            for (int j = 0; j < 4; ++j) {
                int n = nBase + wn * 64 + j * 16 + lr;
                float s = (zn - 2.0f * acc[i][j][r]) + en[j];
                unsigned long long p =
                    ((unsigned long long)__float_as_uint(s) << 32) | (unsigned)n;
                bestp = p < bestp ? p : bestp;
            }
            #pragma unroll
            for (int msk = 1; msk < 16; msk <<= 1) {
                unsigned long long o = shfl_xor_u64(bestp, msk);
                bestp = o < bestp ? o : bestp;
            }
            if (lr == 0) atomicMin(&best[m], bestp);
        }
    }
}

// ---- K3: gather z_q, z_q_st, loss partial, counts, embed_sum scatter --------
__global__ __launch_bounds__(256) void gather_kernel(
        const float* __restrict__ z, const float* __restrict__ cb,
        const unsigned long long* __restrict__ best,
        float* __restrict__ out, float* __restrict__ counts) {
    int t = blockIdx.x;
    int tid = threadIdx.x;
    int idx = (int)(unsigned)(best[t] & 0xFFFFFFFFull);
    const float* zr = z + (size_t)t * C_DIM;
    const float* qr = cb + (size_t)idx * C_DIM;
    float lsum = 0.0f;
    #pragma unroll
    for (int s = 0; s < 2; ++s) {
        int c = tid + s * 256;
        float zf = zr[c], qf = qr[c];
        out[ZQ_OFF + (size_t)t * C_DIM + c] = zf + (qf - zf);
        float d = zf - qf;
        lsum += d * d;
        atomicAdd(&out[NEA_OFF + (size_t)idx * C_DIM + c], zf);  // raw embed_sum
    }
    #pragma unroll
    for (int m = 32; m; m >>= 1) lsum += __shfl_down(lsum, m, 64);
    __shared__ float red[4];
    if ((tid & 63) == 0) red[tid >> 6] = lsum;
    __syncthreads();
    if (tid == 0) {
        float tot = (red[0] + red[1]) + (red[2] + red[3]);
        atomicAdd(&out[LOSS_OFF], tot * (BETA / ((float)T_TOK * (float)C_DIM)));
        out[IDX_OFF + t] = (float)idx;
        atomicAdd(&counts[idx], 1.0f);
    }
}

// ---- K4: new_cluster_size + n = sum(ncs) ------------------------------------
__global__ __launch_bounds__(256) void ncs_kernel(const float* __restrict__ cs,
                                                  const float* __restrict__ counts,
                                                  float* __restrict__ out,
                                                  float* __restrict__ nsum) {
    int k = blockIdx.x * 256 + threadIdx.x;
    float v = cs[k] * DECAY + counts[k] * ONE_MINUS_DECAY;
    out[NCS_OFF + k] = v;
    float s = v;
    #pragma unroll
    for (int m = 32; m; m >>= 1) s += __shfl_down(s, m, 64);
    __shared__ float red[4];
    int tid = threadIdx.x;
    if ((tid & 63) == 0) red[tid >> 6] = s;
    __syncthreads();
    if (tid == 0) atomicAdd(nsum, (red[0] + red[1]) + (red[2] + red[3]));
}

// ---- K5: finalize new_embed_avg (in place) and new_codebook -----------------
__global__ __launch_bounds__(256) void finalize_kernel(const float* __restrict__ ea,
                                                       float* __restrict__ out,
                                                       const float* __restrict__ nsumP) {
    int k = blockIdx.x;
    int tid = threadIdx.x;
    float n = fmaxf(*nsumP, 1.0f);
    float ncs = out[NCS_OFF + k];
    float smoothed = ((ncs + EPS_F) / (n + K_EPS)) * n;
    #pragma unroll
    for (int s = 0; s < 2; ++s) {
        int c = tid + s * 256;
        size_t o = (size_t)k * C_DIM + c;
        float es = out[NEA_OFF + o];
        float nea = ea[o] * DECAY + es * ONE_MINUS_DECAY;
        out[NEA_OFF + o] = nea;
        out[NCB_OFF + o] = nea / smoothed;
    }
}

extern "C" void kernel_launch(void* const* d_in, const int* in_sizes, int n_in,
                              void* d_out, int out_size, void* d_ws, size_t ws_size,
                              hipStream_t stream) {
    const float* z  = (const float*)d_in[0];
    const float* cb = (const float*)d_in[1];
    const float* cs = (const float*)d_in[2];
    const float* ea = (const float*)d_in[3];
    float* out = (float*)d_out;
    float* ws  = (float*)d_ws;
    unsigned long long* best = (unsigned long long*)(ws + WS_BEST);
    _Float16* zp = (_Float16*)out;
    _Float16* cp = (_Float16*)out + CP_HALF_OFF;

    hipMemsetAsync(ws + WS_COUNT, 0, (size_t)(8192 + 2) * 4, stream);  // counts + nsum
    hipMemsetAsync(ws + WS_BEST, 0xFF, (size_t)8192 * 8, stream);      // best = u64 max

    prep_kernel<<<16384, 256, 0, stream>>>(z, cb, zp, cp, ws);
    dist_mfma_kernel<<<4096, 256, 0, stream>>>(zp, cp, ws + WS_ZNORM, ws + WS_ENORM, best);

    // d_out staging regions are now dead; initialize output accumulators
    hipMemsetAsync(out + LOSS_OFF, 0, 4, stream);
    hipMemsetAsync(out + NEA_OFF, 0, (size_t)4194304 * 4, stream);

    gather_kernel<<<8192, 256, 0, stream>>>(z, cb, best, out, ws + WS_COUNT);
    ncs_kernel<<<32, 256, 0, stream>>>(cs, ws + WS_COUNT, out, ws + WS_NSUM);
    finalize_kernel<<<8192, 256, 0, stream>>>(ea, out, ws + WS_NSUM);
}

// Round 3
// 413.499 us; speedup vs baseline: 2.4132x; 1.3619x over previous
//
#include <hip/hip_runtime.h>
#include <cstdint>
#include <cstddef>

// Problem constants
#define T_TOK 8192
#define K_CODE 8192
#define C_DIM 512
#define BETA 0.25f
#define DECAY 0.99f
#define ONE_MINUS_DECAY 0.01f
#define EPS_F 1e-5f
#define K_EPS 0.08192f
// Coarse-dist worst-case error bound: 2*||z||*||e||*2^-10 <= 0.025; margin = 2E + cushion
#define MARGIN 0.0625f

// d_out layout (floats, concatenated in reference return order)
#define ZQ_OFF   ((size_t)0)          // z_q_st      [8,1024,512] = 4194304
#define IDX_OFF  ((size_t)4194304)    // indices     [8,1024]     = 8192
#define LOSS_OFF ((size_t)4202496)    // vq_loss     scalar       = 1
#define NCB_OFF  ((size_t)4202497)    // new_codebook[8192,512]   = 4194304
#define NCS_OFF  ((size_t)8396801)    // new_cluster [8192]       = 8192
#define NEA_OFF  ((size_t)8404993)    // new_embed_avg[8192,512]  = 4194304

// Transient staging inside d_out (all consumed before those regions are written):
//   zp f16[8192*512] = floats [0, 2097152)
//   cp f16[8192*512] = floats [2097152, 4194304)
//   slab1 u64[64*8192] = floats [4194304, 5242880)
//   slab2 u64[64*8192] = floats [5242880, 6291456)
#define CP_F_OFF    ((size_t)2097152)
#define SLAB1_F_OFF ((size_t)4194304)
#define SLAB2_F_OFF ((size_t)5242880)

// d_ws layout (float offsets) — small scratch only
#define WS_ZNORM 0
#define WS_ENORM 8192
#define WS_COUNT 16384
#define WS_NSUM  24576
#define WS_BEST  24578   // u64[8192]; byte offset 98312, 8-aligned

typedef _Float16 half8 __attribute__((ext_vector_type(8)));
typedef float floatx4 __attribute__((ext_vector_type(4)));
typedef unsigned long long ull;

__device__ __forceinline__ void gload16(const void* g, void* l) {
    __builtin_amdgcn_global_load_lds(
        (const __attribute__((address_space(1))) void*)g,
        (__attribute__((address_space(3))) void*)l, 16, 0, 0);
}

__device__ inline ull shfl_xor_u64(ull v, int m) {
    int lo = (int)(unsigned)(v & 0xFFFFFFFFull);
    int hi = (int)(unsigned)(v >> 32);
    lo = __shfl_xor(lo, m, 64);
    hi = __shfl_xor(hi, m, 64);
    return ((ull)(unsigned)hi << 32) | (unsigned)lo;
}
__device__ inline ull umin64(ull a, ull b) { return a < b ? a : b; }
__device__ inline ull umax64(ull a, ull b) { return a > b ? a : b; }

// ---- K1: f16 convert pack + row norms ---------------------------------------
__global__ __launch_bounds__(256) void prep_kernel(const float* __restrict__ z,
                                                   const float* __restrict__ cb,
                                                   _Float16* __restrict__ zp,
                                                   _Float16* __restrict__ cp,
                                                   float* __restrict__ ws) {
    int row = blockIdx.x;           // 0..16383
    int tid = threadIdx.x;
    const float* src;
    _Float16* dst;
    float* nrm;
    if (row < T_TOK) { src = z + (size_t)row * C_DIM; dst = zp + (size_t)row * C_DIM; nrm = ws + WS_ZNORM + row; }
    else { int r = row - T_TOK; src = cb + (size_t)r * C_DIM; dst = cp + (size_t)r * C_DIM; nrm = ws + WS_ENORM + r; }
    float a = src[tid], b = src[tid + 256];
    dst[tid] = (_Float16)a;
    dst[tid + 256] = (_Float16)b;
    float s = a * a + b * b;
    #pragma unroll
    for (int m = 32; m; m >>= 1) s += __shfl_down(s, m, 64);
    __shared__ float red[4];
    if ((tid & 63) == 0) red[tid >> 6] = s;
    __syncthreads();
    if (tid == 0) nrm[0] = (red[0] + red[1]) + (red[2] + red[3]);
}

// ---- K2: coarse f16 MFMA GEMM (K=512) + per-slice top-2 slab ----------------
// 128x128 tile, BK=32. XOR chunk swizzle: chunk slot s of row r holds global
// chunk s ^ ((r>>1)&3) -> frag b128 reads are 2-way bank aliased (free).
__global__ __launch_bounds__(256) void dist_mfma_kernel(
        const _Float16* __restrict__ zp, const _Float16* __restrict__ cp,
        const float* __restrict__ znorm, const float* __restrict__ enorm,
        ull* __restrict__ slab1, ull* __restrict__ slab2) {
    __shared__ __align__(16) _Float16 As[128 * 32];
    __shared__ __align__(16) _Float16 Bs[128 * 32];
    __shared__ ull red2[128][2][2];
    const int tid = threadIdx.x;
    const int w = tid >> 6, lane = tid & 63;
    const int quad = lane >> 4, lr = lane & 15;
    const int wm = w >> 1, wn = w & 1;

    // grouped swizzle for L2 locality
    const int GRID_N = 64, GROUP_M = 16;
    int pid = blockIdx.x;
    int per = GROUP_M * GRID_N;
    int g = pid / per;
    int local = pid % per;
    int bm = g * GROUP_M + (local & (GROUP_M - 1));
    int bn = local / GROUP_M;
    const int mBase = bm * 128, nBase = bn * 128;

    // staging: lane l of instr covering rows [rbase, rbase+16): r = rbase+(l>>2),
    // LDS slot s = l&3 receives global chunk s ^ ((r>>1)&3) = (l&3) ^ ((l>>3)&3)
    int r0 = (w * 2 + 0) * 16 + (lane >> 2);
    int r1 = (w * 2 + 1) * 16 + (lane >> 2);
    int cq = (((lane & 3) ^ ((lane >> 3) & 3))) * 8;
    const _Float16* ga0 = zp + (size_t)(mBase + r0) * C_DIM + cq;
    const _Float16* ga1 = zp + (size_t)(mBase + r1) * C_DIM + cq;
    const _Float16* gb0 = cp + (size_t)(nBase + r0) * C_DIM + cq;
    const _Float16* gb1 = cp + (size_t)(nBase + r1) * C_DIM + cq;
    _Float16* la0 = As + (w * 2 + 0) * 512;
    _Float16* la1 = As + (w * 2 + 1) * 512;
    _Float16* lb0 = Bs + (w * 2 + 0) * 512;
    _Float16* lb1 = Bs + (w * 2 + 1) * 512;

    // frag read: row R = base + lr; chunk 'quad' lives at slot quad ^ ((lr>>1)&3)
    const int slotA = (quad ^ ((lr >> 1) & 3)) * 8;
    const _Float16* aFrag = As + ((size_t)(wm * 64 + lr)) * 32 + slotA;
    const _Float16* bFrag = Bs + ((size_t)(wn * 64 + lr)) * 32 + slotA;

    floatx4 acc[4][4] = {};

    for (int it = 0; it < 16; ++it) {
        __syncthreads();
        gload16(ga0, la0);
        gload16(ga1, la1);
        gload16(gb0, lb0);
        gload16(gb1, lb1);
        ga0 += 32; ga1 += 32; gb0 += 32; gb1 += 32;
        __syncthreads();
        half8 af[4], bf[4];
        #pragma unroll
        for (int i = 0; i < 4; ++i) af[i] = *(const half8*)(aFrag + i * 16 * 32);
        #pragma unroll
        for (int j = 0; j < 4; ++j) bf[j] = *(const half8*)(bFrag + j * 16 * 32);
        #pragma unroll
        for (int i = 0; i < 4; ++i)
            #pragma unroll
            for (int j = 0; j < 4; ++j)
                acc[i][j] = __builtin_amdgcn_mfma_f32_16x16x32_f16(af[i], bf[j], acc[i][j], 0, 0, 0);
    }

    // Epilogue: coarse dist = (zn - 2*dot) + en; per-row top-2 over this
    // block's 128 cols -> slab[bn][row]. C/D: col = lr, row = quad*4 + reg.
    float en[4];
    #pragma unroll
    for (int j = 0; j < 4; ++j) en[j] = enorm[nBase + wn * 64 + j * 16 + lr];
    #pragma unroll
    for (int i = 0; i < 4; ++i) {
        #pragma unroll
        for (int r = 0; r < 4; ++r) {
            int lrow = wm * 64 + i * 16 + quad * 4 + r;
            float zn = znorm[mBase + lrow];
            ull t1 = ~0ull, t2 = ~0ull;
            #pragma unroll
            for (int j = 0; j < 4; ++j) {
                int n = nBase + wn * 64 + j * 16 + lr;
                float s = (zn - 2.0f * acc[i][j][r]) + en[j];
                ull p = ((ull)__float_as_uint(s) << 32) | (unsigned)n;
                if (p < t1) { t2 = t1; t1 = p; } else if (p < t2) t2 = p;
            }
            #pragma unroll
            for (int msk = 1; msk < 16; msk <<= 1) {
                ull o1 = shfl_xor_u64(t1, msk);
                ull o2 = shfl_xor_u64(t2, msk);
                ull n1 = umin64(t1, o1);
                ull n2 = umin64(umax64(t1, o1), umin64(t2, o2));
                t1 = n1; t2 = n2;
            }
            if (lr == 0) { red2[lrow][wn][0] = t1; red2[lrow][wn][1] = t2; }
        }
    }
    __syncthreads();
    if (tid < 128) {
        ull a1 = red2[tid][0][0], a2 = red2[tid][0][1];
        ull b1 = red2[tid][1][0], b2 = red2[tid][1][1];
        ull m1 = umin64(a1, b1);
        ull m2 = umin64(umax64(a1, b1), umin64(a2, b2));
        slab1[(size_t)bn * 8192 + mBase + tid] = m1;
        slab2[(size_t)bn * 8192 + mBase + tid] = m2;
    }
}

// ---- K3: refine — exact fp32 argmin over provably-sufficient candidate set --
__global__ __launch_bounds__(256) void refine_kernel(
        const float* __restrict__ z, const float* __restrict__ cb,
        const float* __restrict__ znorm, const float* __restrict__ enorm,
        const ull* __restrict__ slab1, const ull* __restrict__ slab2,
        ull* __restrict__ best) {
    int t = blockIdx.x;
    int tid = threadIdx.x;
    int wv = tid >> 6, lane = tid & 63;
    __shared__ ull s1[64];
    __shared__ float thrS;
    __shared__ unsigned char fullF[64];
    __shared__ int singles[64];
    __shared__ int scnt;
    __shared__ ull wred[4];

    if (tid < 64) s1[tid] = slab1[(size_t)tid * 8192 + t];
    if (tid == 0) scnt = 0;
    // per-lane slice of the z row (same registers in every wave)
    const float* zr = z + (size_t)t * C_DIM + lane * 8;
    float4 z0 = *(const float4*)zr;
    float4 z1 = *(const float4*)(zr + 4);
    __syncthreads();
    if (tid < 64) {
        ull v = s1[tid];
        #pragma unroll
        for (int m = 32; m; m >>= 1) v = umin64(v, shfl_xor_u64(v, m));
        if (tid == 0) thrS = __uint_as_float((unsigned)(v >> 32)) + MARGIN;
    }
    __syncthreads();
    float thr = thrS;
    if (tid < 64) {
        float d1 = __uint_as_float((unsigned)(s1[tid] >> 32));
        float d2 = __uint_as_float((unsigned)(slab2[(size_t)tid * 8192 + t] >> 32));
        bool full = d2 < thr;
        fullF[tid] = full ? 1 : 0;
        if (!full && d1 < thr) {
            int p = atomicAdd(&scnt, 1);
            singles[p] = (int)(unsigned)(s1[tid] & 0xFFFFFFFFull);
        }
    }
    __syncthreads();
    float zn = znorm[t];
    ull lbest = ~0ull;

    // full-rescan slices: one wave per code, coalesced fp32 row reads
    for (int bn = 0; bn < 64; ++bn) {
        if (!fullF[bn]) continue;
        int nb = bn * 128;
        for (int rep = 0; rep < 32; ++rep) {
            int n = nb + rep * 4 + wv;
            const float* cr = cb + (size_t)n * C_DIM + lane * 8;
            float4 c0 = *(const float4*)cr;
            float4 c1 = *(const float4*)(cr + 4);
            float p = 0.0f;
            p = fmaf(z0.x, c0.x, p); p = fmaf(z0.y, c0.y, p);
            p = fmaf(z0.z, c0.z, p); p = fmaf(z0.w, c0.w, p);
            p = fmaf(z1.x, c1.x, p); p = fmaf(z1.y, c1.y, p);
            p = fmaf(z1.z, c1.z, p); p = fmaf(z1.w, c1.w, p);
            #pragma unroll
            for (int m = 32; m; m >>= 1) p += __shfl_xor(p, m, 64);
            if (lane == 0) {
                float s = (zn - 2.0f * p) + enorm[n];
                ull pk = ((ull)__float_as_uint(s) << 32) | (unsigned)n;
                lbest = umin64(lbest, pk);
            }
        }
    }
    // single-candidate slices
    int sc = scnt;
    for (int base = 0; base < sc; base += 4) {
        int ci = base + wv;
        if (ci < sc) {
            int n = singles[ci];
            const float* cr = cb + (size_t)n * C_DIM + lane * 8;
            float4 c0 = *(const float4*)cr;
            float4 c1 = *(const float4*)(cr + 4);
            float p = 0.0f;
            p = fmaf(z0.x, c0.x, p); p = fmaf(z0.y, c0.y, p);
            p = fmaf(z0.z, c0.z, p); p = fmaf(z0.w, c0.w, p);
            p = fmaf(z1.x, c1.x, p); p = fmaf(z1.y, c1.y, p);
            p = fmaf(z1.z, c1.z, p); p = fmaf(z1.w, c1.w, p);
            #pragma unroll
            for (int m = 32; m; m >>= 1) p += __shfl_xor(p, m, 64);
            if (lane == 0) {
                float s = (zn - 2.0f * p) + enorm[n];
                ull pk = ((ull)__float_as_uint(s) << 32) | (unsigned)n;
                lbest = umin64(lbest, pk);
            }
        }
    }
    if (lane == 0) wred[wv] = lbest;
    __syncthreads();
    if (tid == 0)
        best[t] = umin64(umin64(wred[0], wred[1]), umin64(wred[2], wred[3]));
}

// ---- K4: gather z_q, z_q_st, loss partial, counts, embed_sum scatter --------
__global__ __launch_bounds__(256) void gather_kernel(
        const float* __restrict__ z, const float* __restrict__ cb,
        const ull* __restrict__ best,
        float* __restrict__ out, float* __restrict__ counts) {
    int t = blockIdx.x;
    int tid = threadIdx.x;
    int idx = (int)(unsigned)(best[t] & 0xFFFFFFFFull);
    const float* zr = z + (size_t)t * C_DIM;
    const float* qr = cb + (size_t)idx * C_DIM;
    float lsum = 0.0f;
    #pragma unroll
    for (int s = 0; s < 2; ++s) {
        int c = tid + s * 256;
        float zf = zr[c], qf = qr[c];
        out[ZQ_OFF + (size_t)t * C_DIM + c] = zf + (qf - zf);
        float d = zf - qf;
        lsum += d * d;
        atomicAdd(&out[NEA_OFF + (size_t)idx * C_DIM + c], zf);  // raw embed_sum
    }
    #pragma unroll
    for (int m = 32; m; m >>= 1) lsum += __shfl_down(lsum, m, 64);
    __shared__ float red[4];
    if ((tid & 63) == 0) red[tid >> 6] = lsum;
    __syncthreads();
    if (tid == 0) {
        float tot = (red[0] + red[1]) + (red[2] + red[3]);
        atomicAdd(&out[LOSS_OFF], tot * (BETA / ((float)T_TOK * (float)C_DIM)));
        out[IDX_OFF + t] = (float)idx;
        atomicAdd(&counts[idx], 1.0f);
    }
}

// ---- K5: new_cluster_size + n = sum(ncs) ------------------------------------
__global__ __launch_bounds__(256) void ncs_kernel(const float* __restrict__ cs,
                                                  const float* __restrict__ counts,
                                                  float* __restrict__ out,
                                                  float* __restrict__ nsum) {
    int k = blockIdx.x * 256 + threadIdx.x;
    float v = cs[k] * DECAY + counts[k] * ONE_MINUS_DECAY;
    out[NCS_OFF + k] = v;
    float s = v;
    #pragma unroll
    for (int m = 32; m; m >>= 1) s += __shfl_down(s, m, 64);
    __shared__ float red[4];
    int tid = threadIdx.x;
    if ((tid & 63) == 0) red[tid >> 6] = s;
    __syncthreads();
    if (tid == 0) atomicAdd(nsum, (red[0] + red[1]) + (red[2] + red[3]));
}

// ---- K6: finalize new_embed_avg (in place) and new_codebook -----------------
__global__ __launch_bounds__(256) void finalize_kernel(const float* __restrict__ ea,
                                                       float* __restrict__ out,
                                                       const float* __restrict__ nsumP) {
    int k = blockIdx.x;
    int tid = threadIdx.x;
    float n = fmaxf(*nsumP, 1.0f);
    float ncs = out[NCS_OFF + k];
    float smoothed = ((ncs + EPS_F) / (n + K_EPS)) * n;
    #pragma unroll
    for (int s = 0; s < 2; ++s) {
        int c = tid + s * 256;
        size_t o = (size_t)k * C_DIM + c;
        float es = out[NEA_OFF + o];
        float nea = ea[o] * DECAY + es * ONE_MINUS_DECAY;
        out[NEA_OFF + o] = nea;
        out[NCB_OFF + o] = nea / smoothed;
    }
}

extern "C" void kernel_launch(void* const* d_in, const int* in_sizes, int n_in,
                              void* d_out, int out_size, void* d_ws, size_t ws_size,
                              hipStream_t stream) {
    const float* z  = (const float*)d_in[0];
    const float* cb = (const float*)d_in[1];
    const float* cs = (const float*)d_in[2];
    const float* ea = (const float*)d_in[3];
    float* out = (float*)d_out;
    float* ws  = (float*)d_ws;
    ull* best = (ull*)(ws + WS_BEST);
    _Float16* zp = (_Float16*)out;                 // floats [0, 2097152)
    _Float16* cp = (_Float16*)(out + CP_F_OFF);    // floats [2097152, 4194304)
    ull* slab1 = (ull*)(out + SLAB1_F_OFF);
    ull* slab2 = (ull*)(out + SLAB2_F_OFF);

    hipMemsetAsync(ws + WS_COUNT, 0, (size_t)(8192 + 2) * 4, stream);  // counts + nsum

    prep_kernel<<<16384, 256, 0, stream>>>(z, cb, zp, cp, ws);
    dist_mfma_kernel<<<4096, 256, 0, stream>>>(zp, cp, ws + WS_ZNORM, ws + WS_ENORM, slab1, slab2);
    refine_kernel<<<8192, 256, 0, stream>>>(z, cb, ws + WS_ZNORM, ws + WS_ENORM, slab1, slab2, best);

    // staging/slab regions of d_out are now dead; init output accumulators
    hipMemsetAsync(out + LOSS_OFF, 0, 4, stream);
    hipMemsetAsync(out + NEA_OFF, 0, (size_t)4194304 * 4, stream);

    gather_kernel<<<8192, 256, 0, stream>>>(z, cb, best, out, ws + WS_COUNT);
    ncs_kernel<<<32, 256, 0, stream>>>(cs, ws + WS_COUNT, out, ws + WS_NSUM);
    finalize_kernel<<<8192, 256, 0, stream>>>(ea, out, ws + WS_NSUM);
}

// Round 4
// 391.299 us; speedup vs baseline: 2.5501x; 1.0567x over previous
//
#include <hip/hip_runtime.h>
#include <cstdint>
#include <cstddef>

// Problem constants
#define T_TOK 8192
#define K_CODE 8192
#define C_DIM 512
#define BETA 0.25f
#define DECAY 0.99f
#define ONE_MINUS_DECAY 0.01f
#define EPS_F 1e-5f
#define K_EPS 0.08192f
// Coarse-dist worst-case error bound: 2*||z||*||e||*2^-10 <= 0.025; margin = 2E + cushion
#define MARGIN 0.0625f

// d_out layout (floats, concatenated in reference return order)
#define ZQ_OFF   ((size_t)0)          // z_q_st      [8,1024,512] = 4194304
#define IDX_OFF  ((size_t)4194304)    // indices     [8,1024]     = 8192
#define LOSS_OFF ((size_t)4202496)    // vq_loss     scalar       = 1
#define NCB_OFF  ((size_t)4202497)    // new_codebook[8192,512]   = 4194304
#define NCS_OFF  ((size_t)8396801)    // new_cluster [8192]       = 8192
#define NEA_OFF  ((size_t)8404993)    // new_embed_avg[8192,512]  = 4194304

// Transient regions (all stream-ordered, lifetime-checked):
//   zp f16[8192*512]  = floats [0, 2097152)        dead after dist; ZQ written by refine
//   cp f16[8192*512]  = floats [2097152, 4194304)  dead after dist
//   slab1/slab2 u64[64*8192] each — inside NEA region (8-byte aligned), written
//     by dist, read by refine, dead before finalize writes NEA.
//   list/offsA/offsB int[8192] each — after slabs, written post-refine, read by
//     percode (writes only NCB), clobbered by finalize's NEA write at the end.
#define CP_F_OFF    ((size_t)2097152)
#define SLAB1_F_OFF ((size_t)8404994)               // byte 33619976, 8-aligned
#define SLAB2_F_OFF ((size_t)(8404994 + 1048576))   // 9453570
#define LIST_I_OFF  ((size_t)10502146)
#define OFFSA_I_OFF ((size_t)10510338)
#define OFFSB_I_OFF ((size_t)10518530)

// d_ws layout (float offsets) — small scratch only (~100 KB)
#define WS_ZNORM  0
#define WS_ENORM  8192
#define WS_ICOUNT 16384   // int[8192]
#define WS_NSUM   24576
#define WS_LOSS   24577

typedef _Float16 half8 __attribute__((ext_vector_type(8)));
typedef float floatx4 __attribute__((ext_vector_type(4)));
typedef unsigned long long ull;

__device__ __forceinline__ void gload16(const void* g, void* l) {
    __builtin_amdgcn_global_load_lds(
        (const __attribute__((address_space(1))) void*)g,
        (__attribute__((address_space(3))) void*)l, 16, 0, 0);
}

__device__ inline ull shfl_xor_u64(ull v, int m) {
    int lo = (int)(unsigned)(v & 0xFFFFFFFFull);
    int hi = (int)(unsigned)(v >> 32);
    lo = __shfl_xor(lo, m, 64);
    hi = __shfl_xor(hi, m, 64);
    return ((ull)(unsigned)hi << 32) | (unsigned)lo;
}
__device__ inline ull umin64(ull a, ull b) { return a < b ? a : b; }
__device__ inline ull umax64(ull a, ull b) { return a > b ? a : b; }

// ---- K1: f16 convert pack + row norms ---------------------------------------
__global__ __launch_bounds__(256) void prep_kernel(const float* __restrict__ z,
                                                   const float* __restrict__ cb,
                                                   _Float16* __restrict__ zp,
                                                   _Float16* __restrict__ cp,
                                                   float* __restrict__ ws) {
    int row = blockIdx.x;           // 0..16383
    int tid = threadIdx.x;
    const float* src;
    _Float16* dst;
    float* nrm;
    if (row < T_TOK) { src = z + (size_t)row * C_DIM; dst = zp + (size_t)row * C_DIM; nrm = ws + WS_ZNORM + row; }
    else { int r = row - T_TOK; src = cb + (size_t)r * C_DIM; dst = cp + (size_t)r * C_DIM; nrm = ws + WS_ENORM + r; }
    float a = src[tid], b = src[tid + 256];
    dst[tid] = (_Float16)a;
    dst[tid + 256] = (_Float16)b;
    float s = a * a + b * b;
    #pragma unroll
    for (int m = 32; m; m >>= 1) s += __shfl_down(s, m, 64);
    __shared__ float red[4];
    if ((tid & 63) == 0) red[tid >> 6] = s;
    __syncthreads();
    if (tid == 0) nrm[0] = (red[0] + red[1]) + (red[2] + red[3]);
}

// ---- K2: coarse f16 MFMA GEMM (K=512) + per-slice top-2 slab ----------------
__global__ __launch_bounds__(256) void dist_mfma_kernel(
        const _Float16* __restrict__ zp, const _Float16* __restrict__ cp,
        const float* __restrict__ znorm, const float* __restrict__ enorm,
        ull* __restrict__ slab1, ull* __restrict__ slab2) {
    __shared__ __align__(16) _Float16 As[128 * 32];
    __shared__ __align__(16) _Float16 Bs[128 * 32];
    __shared__ ull red2[128][2][2];
    const int tid = threadIdx.x;
    const int w = tid >> 6, lane = tid & 63;
    const int quad = lane >> 4, lr = lane & 15;
    const int wm = w >> 1, wn = w & 1;

    const int GRID_N = 64, GROUP_M = 16;
    int pid = blockIdx.x;
    int per = GROUP_M * GRID_N;
    int g = pid / per;
    int local = pid % per;
    int bm = g * GROUP_M + (local & (GROUP_M - 1));
    int bn = local / GROUP_M;
    const int mBase = bm * 128, nBase = bn * 128;

    int r0 = (w * 2 + 0) * 16 + (lane >> 2);
    int r1 = (w * 2 + 1) * 16 + (lane >> 2);
    int cq = (((lane & 3) ^ ((lane >> 3) & 3))) * 8;
    const _Float16* ga0 = zp + (size_t)(mBase + r0) * C_DIM + cq;
    const _Float16* ga1 = zp + (size_t)(mBase + r1) * C_DIM + cq;
    const _Float16* gb0 = cp + (size_t)(nBase + r0) * C_DIM + cq;
    const _Float16* gb1 = cp + (size_t)(nBase + r1) * C_DIM + cq;
    _Float16* la0 = As + (w * 2 + 0) * 512;
    _Float16* la1 = As + (w * 2 + 1) * 512;
    _Float16* lb0 = Bs + (w * 2 + 0) * 512;
    _Float16* lb1 = Bs + (w * 2 + 1) * 512;

    const int slotA = (quad ^ ((lr >> 1) & 3)) * 8;
    const _Float16* aFrag = As + ((size_t)(wm * 64 + lr)) * 32 + slotA;
    const _Float16* bFrag = Bs + ((size_t)(wn * 64 + lr)) * 32 + slotA;

    floatx4 acc[4][4] = {};

    for (int it = 0; it < 16; ++it) {
        __syncthreads();
        gload16(ga0, la0);
        gload16(ga1, la1);
        gload16(gb0, lb0);
        gload16(gb1, lb1);
        ga0 += 32; ga1 += 32; gb0 += 32; gb1 += 32;
        __syncthreads();
        half8 af[4], bf[4];
        #pragma unroll
        for (int i = 0; i < 4; ++i) af[i] = *(const half8*)(aFrag + i * 16 * 32);
        #pragma unroll
        for (int j = 0; j < 4; ++j) bf[j] = *(const half8*)(bFrag + j * 16 * 32);
        #pragma unroll
        for (int i = 0; i < 4; ++i)
            #pragma unroll
            for (int j = 0; j < 4; ++j)
                acc[i][j] = __builtin_amdgcn_mfma_f32_16x16x32_f16(af[i], bf[j], acc[i][j], 0, 0, 0);
    }

    float en[4];
    #pragma unroll
    for (int j = 0; j < 4; ++j) en[j] = enorm[nBase + wn * 64 + j * 16 + lr];
    #pragma unroll
    for (int i = 0; i < 4; ++i) {
        #pragma unroll
        for (int r = 0; r < 4; ++r) {
            int lrow = wm * 64 + i * 16 + quad * 4 + r;
            float zn = znorm[mBase + lrow];
            ull t1 = ~0ull, t2 = ~0ull;
            #pragma unroll
            for (int j = 0; j < 4; ++j) {
                int n = nBase + wn * 64 + j * 16 + lr;
                float s = (zn - 2.0f * acc[i][j][r]) + en[j];
                ull p = ((ull)__float_as_uint(s) << 32) | (unsigned)n;
                if (p < t1) { t2 = t1; t1 = p; } else if (p < t2) t2 = p;
            }
            #pragma unroll
            for (int msk = 1; msk < 16; msk <<= 1) {
                ull o1 = shfl_xor_u64(t1, msk);
                ull o2 = shfl_xor_u64(t2, msk);
                ull n1 = umin64(t1, o1);
                ull n2 = umin64(umax64(t1, o1), umin64(t2, o2));
                t1 = n1; t2 = n2;
            }
            if (lr == 0) { red2[lrow][wn][0] = t1; red2[lrow][wn][1] = t2; }
        }
    }
    __syncthreads();
    if (tid < 128) {
        ull a1 = red2[tid][0][0], a2 = red2[tid][0][1];
        ull b1 = red2[tid][1][0], b2 = red2[tid][1][1];
        ull m1 = umin64(a1, b1);
        ull m2 = umin64(umax64(a1, b1), umin64(a2, b2));
        slab1[(size_t)bn * 8192 + mBase + tid] = m1;
        slab2[(size_t)bn * 8192 + mBase + tid] = m2;
    }
}

// ---- K3: refine + fused gather --------------------------------------------
// Exact fp32 argmin over provably-sufficient candidates, then (wave 0) gather
// cb[idx], write z_q_st, loss partial, idx output, histogram bump.
__global__ __launch_bounds__(256) void refine_gather_kernel(
        const float* __restrict__ z, const float* __restrict__ cb,
        const float* __restrict__ znorm, const float* __restrict__ enorm,
        const ull* __restrict__ slab1, const ull* __restrict__ slab2,
        float* __restrict__ out, int* __restrict__ icount,
        float* __restrict__ lossAcc) {
    int t = blockIdx.x;
    int tid = threadIdx.x;
    int wv = tid >> 6, lane = tid & 63;
    __shared__ ull s1[64];
    __shared__ float thrS;
    __shared__ unsigned char fullF[64];
    __shared__ int singles[64];
    __shared__ int scnt;
    __shared__ ull wred[4];
    __shared__ ull sbestS;

    if (tid < 64) s1[tid] = slab1[(size_t)tid * 8192 + t];
    if (tid == 0) scnt = 0;
    const float* zr = z + (size_t)t * C_DIM + lane * 8;
    float4 z0 = *(const float4*)zr;
    float4 z1 = *(const float4*)(zr + 4);
    __syncthreads();
    if (tid < 64) {
        ull v = s1[tid];
        #pragma unroll
        for (int m = 32; m; m >>= 1) v = umin64(v, shfl_xor_u64(v, m));
        if (tid == 0) thrS = __uint_as_float((unsigned)(v >> 32)) + MARGIN;
    }
    __syncthreads();
    float thr = thrS;
    if (tid < 64) {
        float d1 = __uint_as_float((unsigned)(s1[tid] >> 32));
        float d2 = __uint_as_float((unsigned)(slab2[(size_t)tid * 8192 + t] >> 32));
        bool full = d2 < thr;
        fullF[tid] = full ? 1 : 0;
        if (!full && d1 < thr) {
            int p = atomicAdd(&scnt, 1);
            singles[p] = (int)(unsigned)(s1[tid] & 0xFFFFFFFFull);
        }
    }
    __syncthreads();
    float zn = znorm[t];
    ull lbest = ~0ull;

    for (int bn = 0; bn < 64; ++bn) {
        if (!fullF[bn]) continue;
        int nb = bn * 128;
        for (int rep = 0; rep < 32; ++rep) {
            int n = nb + rep * 4 + wv;
            const float* cr = cb + (size_t)n * C_DIM + lane * 8;
            float4 c0 = *(const float4*)cr;
            float4 c1 = *(const float4*)(cr + 4);
            float p = 0.0f;
            p = fmaf(z0.x, c0.x, p); p = fmaf(z0.y, c0.y, p);
            p = fmaf(z0.z, c0.z, p); p = fmaf(z0.w, c0.w, p);
            p = fmaf(z1.x, c1.x, p); p = fmaf(z1.y, c1.y, p);
            p = fmaf(z1.z, c1.z, p); p = fmaf(z1.w, c1.w, p);
            #pragma unroll
            for (int m = 32; m; m >>= 1) p += __shfl_xor(p, m, 64);
            if (lane == 0) {
                float s = (zn - 2.0f * p) + enorm[n];
                ull pk = ((ull)__float_as_uint(s) << 32) | (unsigned)n;
                lbest = umin64(lbest, pk);
            }
        }
    }
    int sc = scnt;
    for (int base = 0; base < sc; base += 4) {
        int ci = base + wv;
        if (ci < sc) {
            int n = singles[ci];
            const float* cr = cb + (size_t)n * C_DIM + lane * 8;
            float4 c0 = *(const float4*)cr;
            float4 c1 = *(const float4*)(cr + 4);
            float p = 0.0f;
            p = fmaf(z0.x, c0.x, p); p = fmaf(z0.y, c0.y, p);
            p = fmaf(z0.z, c0.z, p); p = fmaf(z0.w, c0.w, p);
            p = fmaf(z1.x, c1.x, p); p = fmaf(z1.y, c1.y, p);
            p = fmaf(z1.z, c1.z, p); p = fmaf(z1.w, c1.w, p);
            #pragma unroll
            for (int m = 32; m; m >>= 1) p += __shfl_xor(p, m, 64);
            if (lane == 0) {
                float s = (zn - 2.0f * p) + enorm[n];
                ull pk = ((ull)__float_as_uint(s) << 32) | (unsigned)n;
                lbest = umin64(lbest, pk);
            }
        }
    }
    if (lane == 0) wred[wv] = lbest;
    __syncthreads();
    if (tid == 0)
        sbestS = umin64(umin64(wred[0], wred[1]), umin64(wred[2], wred[3]));
    __syncthreads();
    int idx = (int)(unsigned)(sbestS & 0xFFFFFFFFull);

    // fused gather: wave 0 holds the full z row (lane==tid for tid<64)
    if (tid < 64) {
        const float* qr = cb + (size_t)idx * C_DIM + tid * 8;
        float4 q0 = *(const float4*)qr;
        float4 q1 = *(const float4*)(qr + 4);
        float4 o0, o1;
        o0.x = z0.x + (q0.x - z0.x); o0.y = z0.y + (q0.y - z0.y);
        o0.z = z0.z + (q0.z - z0.z); o0.w = z0.w + (q0.w - z0.w);
        o1.x = z1.x + (q1.x - z1.x); o1.y = z1.y + (q1.y - z1.y);
        o1.z = z1.z + (q1.z - z1.z); o1.w = z1.w + (q1.w - z1.w);
        float* zq = out + ZQ_OFF + (size_t)t * C_DIM + tid * 8;
        *(float4*)zq = o0;
        *(float4*)(zq + 4) = o1;
        float d, l = 0.0f;
        d = z0.x - q0.x; l = fmaf(d, d, l);
        d = z0.y - q0.y; l = fmaf(d, d, l);
        d = z0.z - q0.z; l = fmaf(d, d, l);
        d = z0.w - q0.w; l = fmaf(d, d, l);
        d = z1.x - q1.x; l = fmaf(d, d, l);
        d = z1.y - q1.y; l = fmaf(d, d, l);
        d = z1.z - q1.z; l = fmaf(d, d, l);
        d = z1.w - q1.w; l = fmaf(d, d, l);
        #pragma unroll
        for (int m = 32; m; m >>= 1) l += __shfl_down(l, m, 64);
        if (tid == 0) {
            atomicAdd(lossAcc, l * (BETA / ((float)T_TOK * (float)C_DIM)));
            out[IDX_OFF + t] = (float)idx;
            atomicAdd(&icount[idx], 1);
        }
    }
}

// ---- K4: exclusive prefix scan of histogram (single block) ------------------
__global__ __launch_bounds__(256) void scan_kernel(const int* __restrict__ icount,
                                                   int* __restrict__ offsA,
                                                   int* __restrict__ offsB) {
    __shared__ int tot[256];
    int tid = threadIdx.x;
    int v[32];
    int s = 0;
    #pragma unroll
    for (int j = 0; j < 32; ++j) {
        int x = icount[tid * 32 + j];
        v[j] = s;
        s += x;
    }
    tot[tid] = s;
    __syncthreads();
    for (int d = 1; d < 256; d <<= 1) {
        int x = (tid >= d) ? tot[tid - d] : 0;
        __syncthreads();
        tot[tid] += x;
        __syncthreads();
    }
    int excl = tid ? tot[tid - 1] : 0;
    #pragma unroll
    for (int j = 0; j < 32; ++j) {
        int o = excl + v[j];
        offsA[tid * 32 + j] = o;
        offsB[tid * 32 + j] = o;
    }
}

// ---- K5: scatter token ids into per-code buckets ----------------------------
__global__ __launch_bounds__(256) void scatter_kernel(const float* __restrict__ out,
                                                      int* __restrict__ offsA,
                                                      int* __restrict__ list) {
    int t = blockIdx.x * 256 + threadIdx.x;
    int idx = (int)out[IDX_OFF + t];
    int slot = atomicAdd(&offsA[idx], 1);
    list[slot] = t;
}

// ---- K6: new_cluster_size + nsum + loss copy --------------------------------
__global__ __launch_bounds__(256) void ncs_kernel(const float* __restrict__ cs,
                                                  const int* __restrict__ icount,
                                                  float* __restrict__ out,
                                                  float* __restrict__ nsum,
                                                  const float* __restrict__ lossAcc) {
    int k = blockIdx.x * 256 + threadIdx.x;
    float v = cs[k] * DECAY + (float)icount[k] * ONE_MINUS_DECAY;
    out[NCS_OFF + k] = v;
    float s = v;
    #pragma unroll
    for (int m = 32; m; m >>= 1) s += __shfl_down(s, m, 64);
    __shared__ float red[4];
    int tid = threadIdx.x;
    if ((tid & 63) == 0) red[tid >> 6] = s;
    __syncthreads();
    if (tid == 0) atomicAdd(nsum, (red[0] + red[1]) + (red[2] + red[3]));
    if (blockIdx.x == 0 && tid == 0) out[LOSS_OFF] = lossAcc[0];
}

// ---- K7: per-code segment sum (embed_sum) -> staged in NCB region -----------
__global__ __launch_bounds__(256) void percode_sum_kernel(
        const float* __restrict__ z, const int* __restrict__ list,
        const int* __restrict__ offsB, const int* __restrict__ icount,
        float* __restrict__ out) {
    int k = blockIdx.x;
    int tid = threadIdx.x;
    int off = offsB[k], cnt = icount[k];
    float a0 = 0.0f, a1 = 0.0f;
    for (int i = 0; i < cnt; ++i) {
        int t = list[off + i];
        const float* zrow = z + (size_t)t * C_DIM;
        a0 += zrow[tid];
        a1 += zrow[tid + 256];
    }
    out[NCB_OFF + (size_t)k * C_DIM + tid] = a0;
    out[NCB_OFF + (size_t)k * C_DIM + tid + 256] = a1;
}

// ---- K8: finalize new_embed_avg and new_codebook ----------------------------
__global__ __launch_bounds__(256) void finalize_kernel(const float* __restrict__ ea,
                                                       float* __restrict__ out,
                                                       const float* __restrict__ nsumP) {
    int k = blockIdx.x;
    int tid = threadIdx.x;
    float n = fmaxf(*nsumP, 1.0f);
    float ncs = out[NCS_OFF + k];
    float smoothed = ((ncs + EPS_F) / (n + K_EPS)) * n;
    #pragma unroll
    for (int s = 0; s < 2; ++s) {
        int c = tid + s * 256;
        size_t o = (size_t)k * C_DIM + c;
        float es = out[NCB_OFF + o];                       // staged embed_sum
        float nea = ea[o] * DECAY + es * ONE_MINUS_DECAY;
        out[NEA_OFF + o] = nea;
        out[NCB_OFF + o] = nea / smoothed;
    }
}

extern "C" void kernel_launch(void* const* d_in, const int* in_sizes, int n_in,
                              void* d_out, int out_size, void* d_ws, size_t ws_size,
                              hipStream_t stream) {
    const float* z  = (const float*)d_in[0];
    const float* cb = (const float*)d_in[1];
    const float* cs = (const float*)d_in[2];
    const float* ea = (const float*)d_in[3];
    float* out = (float*)d_out;
    float* ws  = (float*)d_ws;
    _Float16* zp = (_Float16*)out;
    _Float16* cp = (_Float16*)(out + CP_F_OFF);
    ull* slab1 = (ull*)(out + SLAB1_F_OFF);
    ull* slab2 = (ull*)(out + SLAB2_F_OFF);
    int* list  = (int*)(out + LIST_I_OFF);
    int* offsA = (int*)(out + OFFSA_I_OFF);
    int* offsB = (int*)(out + OFFSB_I_OFF);
    int* icount = (int*)(ws + WS_ICOUNT);
    float* nsum = ws + WS_NSUM;
    float* lossAcc = ws + WS_LOSS;

    hipMemsetAsync(ws + WS_ICOUNT, 0, (size_t)(8192 + 2) * 4, stream);  // icount + nsum + loss

    prep_kernel<<<16384, 256, 0, stream>>>(z, cb, zp, cp, ws);
    dist_mfma_kernel<<<4096, 256, 0, stream>>>(zp, cp, ws + WS_ZNORM, ws + WS_ENORM, slab1, slab2);
    refine_gather_kernel<<<8192, 256, 0, stream>>>(z, cb, ws + WS_ZNORM, ws + WS_ENORM,
                                                   slab1, slab2, out, icount, lossAcc);
    scan_kernel<<<1, 256, 0, stream>>>(icount, offsA, offsB);
    scatter_kernel<<<32, 256, 0, stream>>>(out, offsA, list);
    ncs_kernel<<<32, 256, 0, stream>>>(cs, icount, out, nsum, lossAcc);
    percode_sum_kernel<<<8192, 256, 0, stream>>>(z, list, offsB, icount, out);
    finalize_kernel<<<8192, 256, 0, stream>>>(ea, out, nsum);
}